// Round 6
// baseline (222.430 us; speedup 1.0000x reference)
//
#include <hip/hip_runtime.h>
#include <hip/hip_fp16.h>

#define D_ 160
#define H_ 192
#define W_ 160
constexpr int NV = D_ * H_ * W_;   // 4,915,200 (even)

typedef float        f32x4 __attribute__((ext_vector_type(4)));
typedef unsigned int u32x4 __attribute__((ext_vector_type(4)));

// ---------------------------------------------------------------------------
// Pass 1: convert vol f32[NV][4] -> packed half4 (uint2) in d_ws.
// XCD-swizzled so each XCD converts the same z-slab it will later gather from.
// ---------------------------------------------------------------------------
__global__ __launch_bounds__(256) void vol_to_half_kernel(
    const float4* __restrict__ vol, uint4* __restrict__ volh2)
{
    // 9600 blocks, 9600 % 8 == 0 -> bijective XCD chunking
    unsigned bid = blockIdx.x;
    unsigned nb  = (bid & 7u) * 1200u + (bid >> 3);
    int i = (int)(nb * 256u + threadIdx.x);   // pair index
    if (i >= NV / 2) return;
    f32x4 a = __builtin_nontemporal_load((const f32x4*)(vol + 2 * i));
    f32x4 b = __builtin_nontemporal_load((const f32x4*)(vol + 2 * i + 1));
    __half2 a01 = __floats2half2_rn(a.x, a.y);
    __half2 a23 = __floats2half2_rn(a.z, a.w);
    __half2 b01 = __floats2half2_rn(b.x, b.y);
    __half2 b23 = __floats2half2_rn(b.z, b.w);
    uint4 p;
    p.x = *(unsigned int*)&a01;
    p.y = *(unsigned int*)&a23;
    p.z = *(unsigned int*)&b01;
    p.w = *(unsigned int*)&b23;
    volh2[i] = p;
}

__device__ inline float4 h4_to_f4(uint2 p) {
    __half2 ab = *(__half2*)&p.x;
    __half2 cd = *(__half2*)&p.y;
    float2 f0 = __half22float2(ab);
    float2 f1 = __half22float2(cd);
    return make_float4(f0.x, f0.y, f1.x, f1.y);
}

// Per-voxel gather setup: 4 row-pair base offsets + 6 weights.
// Edge trick: at the x-clamp edge (ix0 == W-1, both corners v[W-1], weights
// sum to 1) the reference result is exactly v[W-1]; we load row[W-2..W-1]
// and force (wx0,wx1) = (0,1) so the high half carries the whole weight.
struct VoxSetup {
    int b00, b01, b10, b11;
    float wz0, wz1, wy0, wy1, wx0, wx1;
};

__device__ inline VoxSetup setup_voxel(int x, int y, int z,
                                       float dz, float dy, float dx)
{
    float lz = (float)z + dz;
    float ly = (float)y + dy;
    float lx = (float)x + dx;

    // Reference: loc0c = clip(floor(loc), 0, max); loc1 = clip(loc0c+1, 0, max)
    float z0f = fminf(fmaxf(floorf(lz), 0.f), (float)(D_ - 1));
    float y0f = fminf(fmaxf(floorf(ly), 0.f), (float)(H_ - 1));
    float x0f = fminf(fmaxf(floorf(lx), 0.f), (float)(W_ - 1));
    float z1f = fminf(z0f + 1.f, (float)(D_ - 1));
    float y1f = fminf(y0f + 1.f, (float)(H_ - 1));
    float x1f = fminf(x0f + 1.f, (float)(W_ - 1));

    VoxSetup s;
    s.wz0 = z1f - lz; s.wz1 = 1.f - s.wz0;
    s.wy0 = y1f - ly; s.wy1 = 1.f - s.wy0;

    int ix0 = (int)x0f;
    bool edge = ix0 >= W_ - 1;
    int a = edge ? W_ - 2 : ix0;
    float wx0 = x1f - lx;
    s.wx0 = edge ? 0.f : wx0;   // edge: result is exactly the high half
    s.wx1 = 1.f - s.wx0;

    int iz0 = (int)z0f, iz1 = (int)z1f;
    int iy0 = (int)y0f, iy1 = (int)y1f;
    s.b00 = (iz0 * H_ + iy0) * W_ + a;
    s.b01 = (iz0 * H_ + iy1) * W_ + a;
    s.b10 = (iz1 * H_ + iy0) * W_ + a;
    s.b11 = (iz1 * H_ + iy1) * W_ + a;
    return s;
}

// Reduce 4 loaded row-pairs (lo = x0 corner, hi = x1 corner) with weights.
__device__ inline f32x4 reduce_voxel(const VoxSetup& s,
                                     u32x4 q00, u32x4 q01, u32x4 q10, u32x4 q11)
{
    uint2 l00, h00, l01, h01, l10, h10, l11, h11;
    l00.x = q00[0]; l00.y = q00[1]; h00.x = q00[2]; h00.y = q00[3];
    l01.x = q01[0]; l01.y = q01[1]; h01.x = q01[2]; h01.y = q01[3];
    l10.x = q10[0]; l10.y = q10[1]; h10.x = q10[2]; h10.y = q10[3];
    l11.x = q11[0]; l11.y = q11[1]; h11.x = q11[2]; h11.y = q11[3];

    float4 v000 = h4_to_f4(l00), v001 = h4_to_f4(h00);
    float4 v010 = h4_to_f4(l01), v011 = h4_to_f4(h01);
    float4 v100 = h4_to_f4(l10), v101 = h4_to_f4(h10);
    float4 v110 = h4_to_f4(l11), v111 = h4_to_f4(h11);

    float w000 = s.wz0 * s.wy0 * s.wx0;
    float w001 = s.wz0 * s.wy0 * s.wx1;
    float w010 = s.wz0 * s.wy1 * s.wx0;
    float w011 = s.wz0 * s.wy1 * s.wx1;
    float w100 = s.wz1 * s.wy0 * s.wx0;
    float w101 = s.wz1 * s.wy0 * s.wx1;
    float w110 = s.wz1 * s.wy1 * s.wx0;
    float w111 = s.wz1 * s.wy1 * s.wx1;

    f32x4 r;
    r.x = w000 * v000.x + w001 * v001.x + w010 * v010.x + w011 * v011.x
        + w100 * v100.x + w101 * v101.x + w110 * v110.x + w111 * v111.x;
    r.y = w000 * v000.y + w001 * v001.y + w010 * v010.y + w011 * v011.y
        + w100 * v100.y + w101 * v101.y + w110 * v110.y + w111 * v111.y;
    r.z = w000 * v000.z + w001 * v001.z + w010 * v010.z + w011 * v011.z
        + w100 * v100.z + w101 * v101.z + w110 * v110.z + w111 * v111.z;
    r.w = w000 * v000.w + w001 * v001.w + w010 * v010.w + w011 * v011.w
        + w100 * v100.w + w101 * v101.w + w110 * v110.w + w111 * v111.w;
    return r;
}

// ---------------------------------------------------------------------------
// Pass 2: trilinear gather, software-pipelined x-sweep.
// Block = 256 threads covering a 16x4x4 tile (16 x-contiguous lanes -> fully
// coalesced df/out, R4's proven mapping). Each block sweeps all 10 x-tiles of
// its (y,z) row-band with a depth-2 pipeline:
//   df(bx+1) prefetch  ||  setup+gather(bx)  ||  reduce+store(bx-1).
// Gathers issued in iter i are consumed in iter i+1, so the DATAFLOW forces
// ~7 loads/wave in flight (R4/R5 lesson: straight-line issue-all gets
// serialized by the register-minimizing scheduler; a pipelined loop cannot
// be). Fully unrolled -> all indices static, copies become SSA renames.
// Grid 48*40 = 1920 blocks, XCD-chunked (240/XCD): bz in [5k,5k+5) ->
// z in [20k,20k+20), matching pass 1's slab map. 1920 % 8 == 0 (bijective).
// ---------------------------------------------------------------------------
__global__ __launch_bounds__(256) void st_half_kernel(
    const uint2* __restrict__ volh,   // [D,H,W] of half4 (8 B)
    const float* __restrict__ df,     // [D,H,W,3]
    float*       __restrict__ out)    // [D,H,W,4] f32
{
    unsigned bid = blockIdx.x;                 // 1920 blocks
    unsigned nb  = (bid & 7u) * 240u + (bid >> 3);
    int by = (int)(nb % 48u);
    int bz = (int)(nb / 48u);                  // in [5k, 5k+5) for XCD k

    int tid = threadIdx.x;
    int lx  = tid & 15;
    int y   = by * 4 + ((tid >> 4) & 3);
    int z   = bz * 4 + (tid >> 6);
    int rowbase = (z * H_ + y) * W_;

    // prologue: df for tile 0
    float dzC, dyC, dxC;
    {
        const float* p = df + 3 * (size_t)(rowbase + lx);
        dzC = __builtin_nontemporal_load(p + 0);
        dyC = __builtin_nontemporal_load(p + 1);
        dxC = __builtin_nontemporal_load(p + 2);
    }

    VoxSetup sP;
    u32x4 qp0, qp1, qp2, qp3;

    #pragma unroll
    for (int bx = 0; bx < 10; ++bx) {
        // stage A: prefetch df for tile bx+1
        float dzN = 0.f, dyN = 0.f, dxN = 0.f;
        if (bx < 9) {
            const float* p = df + 3 * (size_t)(rowbase + (bx + 1) * 16 + lx);
            dzN = __builtin_nontemporal_load(p + 0);
            dyN = __builtin_nontemporal_load(p + 1);
            dxN = __builtin_nontemporal_load(p + 2);
        }
        // stage B: setup + issue 4 paired gathers for tile bx
        VoxSetup sC = setup_voxel(bx * 16 + lx, y, z, dzC, dyC, dxC);
        u32x4 qc0, qc1, qc2, qc3;
        __builtin_memcpy(&qc0, volh + sC.b00, 16);
        __builtin_memcpy(&qc1, volh + sC.b01, 16);
        __builtin_memcpy(&qc2, volh + sC.b10, 16);
        __builtin_memcpy(&qc3, volh + sC.b11, 16);
        // stage C: reduce + store tile bx-1 (its gathers have a full
        // iteration of latency slack behind them)
        if (bx > 0) {
            f32x4 r = reduce_voxel(sP, qp0, qp1, qp2, qp3);
            __builtin_nontemporal_store(
                r, (f32x4*)(out + 4 * (size_t)(rowbase + (bx - 1) * 16 + lx)));
        }
        // rotate pipeline registers (SSA renames after full unroll)
        sP = sC; qp0 = qc0; qp1 = qc1; qp2 = qc2; qp3 = qc3;
        dzC = dzN; dyC = dyN; dxC = dxN;
    }
    // epilogue: tile 9
    {
        f32x4 r = reduce_voxel(sP, qp0, qp1, qp2, qp3);
        __builtin_nontemporal_store(
            r, (f32x4*)(out + 4 * (size_t)(rowbase + 9 * 16 + lx)));
    }
}

// ---------------------------------------------------------------------------
// Fallback (ws too small): pure-f32 gather kernel.
// ---------------------------------------------------------------------------
__global__ __launch_bounds__(256) void st_f32_kernel(
    const float4* __restrict__ vol,
    const float*  __restrict__ df,
    float4*       __restrict__ out)
{
    int tid = threadIdx.x;
    int x = blockIdx.x * 16 + (tid & 15);
    int y = blockIdx.y * 4  + ((tid >> 4) & 3);
    int z = blockIdx.z * 4  + (tid >> 6);
    int idx = (z * H_ + y) * W_ + x;

    float dz = df[3 * idx + 0];
    float dy = df[3 * idx + 1];
    float dx = df[3 * idx + 2];
    float lz = (float)z + dz, ly = (float)y + dy, lx = (float)x + dx;

    float z0f = fminf(fmaxf(floorf(lz), 0.f), (float)(D_ - 1));
    float y0f = fminf(fmaxf(floorf(ly), 0.f), (float)(H_ - 1));
    float x0f = fminf(fmaxf(floorf(lx), 0.f), (float)(W_ - 1));
    float z1f = fminf(z0f + 1.f, (float)(D_ - 1));
    float y1f = fminf(y0f + 1.f, (float)(H_ - 1));
    float x1f = fminf(x0f + 1.f, (float)(W_ - 1));

    float wz0 = z1f - lz, wz1 = 1.f - wz0;
    float wy0 = y1f - ly, wy1 = 1.f - wy0;
    float wx0 = x1f - lx, wx1 = 1.f - wx0;

    int iz0 = (int)z0f, iz1 = (int)z1f;
    int iy0 = (int)y0f, iy1 = (int)y1f;
    int ix0 = (int)x0f, ix1 = (int)x1f;

    int b00 = (iz0 * H_ + iy0) * W_;
    int b01 = (iz0 * H_ + iy1) * W_;
    int b10 = (iz1 * H_ + iy0) * W_;
    int b11 = (iz1 * H_ + iy1) * W_;

    float4 v000 = vol[b00 + ix0];
    float4 v001 = vol[b00 + ix1];
    float4 v010 = vol[b01 + ix0];
    float4 v011 = vol[b01 + ix1];
    float4 v100 = vol[b10 + ix0];
    float4 v101 = vol[b10 + ix1];
    float4 v110 = vol[b11 + ix0];
    float4 v111 = vol[b11 + ix1];

    float w000 = wz0*wy0*wx0, w001 = wz0*wy0*wx1;
    float w010 = wz0*wy1*wx0, w011 = wz0*wy1*wx1;
    float w100 = wz1*wy0*wx0, w101 = wz1*wy0*wx1;
    float w110 = wz1*wy1*wx0, w111 = wz1*wy1*wx1;

    float4 r;
    r.x = w000*v000.x + w001*v001.x + w010*v010.x + w011*v011.x
        + w100*v100.x + w101*v101.x + w110*v110.x + w111*v111.x;
    r.y = w000*v000.y + w001*v001.y + w010*v010.y + w011*v011.y
        + w100*v100.y + w101*v101.y + w110*v110.y + w111*v111.y;
    r.z = w000*v000.z + w001*v001.z + w010*v010.z + w011*v011.z
        + w100*v100.z + w101*v101.z + w110*v110.z + w111*v111.z;
    r.w = w000*v000.w + w001*v001.w + w010*v010.w + w011*v011.w
        + w100*v100.w + w101*v101.w + w110*v110.w + w111*v111.w;

    out[idx] = r;
}

extern "C" void kernel_launch(void* const* d_in, const int* in_sizes, int n_in,
                              void* d_out, int out_size, void* d_ws, size_t ws_size,
                              hipStream_t stream) {
    const float4* vol = (const float4*)d_in[0];  // (160,192,160,4) f32
    const float*  df  = (const float*)d_in[1];   // (160,192,160,3) f32
    float4* out = (float4*)d_out;

    size_t need = (size_t)NV * 8;  // half4 per voxel
    if (ws_size >= need) {
        int pairs = NV / 2;                       // 2,457,600 -> 9600 blocks
        vol_to_half_kernel<<<pairs / 256, 256, 0, stream>>>(
            vol, (uint4*)d_ws);
        st_half_kernel<<<1920, 256, 0, stream>>>(
            (const uint2*)d_ws, df, (float*)out);
    } else {
        dim3 grid(W_ / 16, H_ / 4, D_ / 4);       // 10 x 48 x 40
        st_f32_kernel<<<grid, 256, 0, stream>>>(vol, df, out);
    }
}

// Round 7
// 210.464 us; speedup vs baseline: 1.0569x; 1.0569x over previous
//
#include <hip/hip_runtime.h>
#include <hip/hip_fp16.h>

#define D_ 160
#define H_ 192
#define W_ 160
constexpr int NV = D_ * H_ * W_;   // 4,915,200 (even)

// Staged window (half4 voxels): 24 x 14 x 16 = 43,008 B of LDS.
// Tile 16x4x8 + effective halo >= ~4 on every side for every lane.
#define WX 24
#define WY 14
#define WZ 16
#define NSTAGE ((WX / 2) * WY * WZ / 64)   // 16B chunks / 64 lanes = 42 calls

typedef float        f32x4 __attribute__((ext_vector_type(4)));
typedef unsigned int u32x4 __attribute__((ext_vector_type(4)));

// ---------------------------------------------------------------------------
// Pass 1: convert vol f32[NV][4] -> packed half4 (uint2) in d_ws.
// XCD-swizzled so each XCD converts the same z-slab it will later gather from.
// ---------------------------------------------------------------------------
__global__ __launch_bounds__(256) void vol_to_half_kernel(
    const float4* __restrict__ vol, uint4* __restrict__ volh2)
{
    // 9600 blocks, 9600 % 8 == 0 -> bijective XCD chunking
    unsigned bid = blockIdx.x;
    unsigned nb  = (bid & 7u) * 1200u + (bid >> 3);
    int i = (int)(nb * 256u + threadIdx.x);   // pair index
    if (i >= NV / 2) return;
    f32x4 a = __builtin_nontemporal_load((const f32x4*)(vol + 2 * i));
    f32x4 b = __builtin_nontemporal_load((const f32x4*)(vol + 2 * i + 1));
    __half2 a01 = __floats2half2_rn(a.x, a.y);
    __half2 a23 = __floats2half2_rn(a.z, a.w);
    __half2 b01 = __floats2half2_rn(b.x, b.y);
    __half2 b23 = __floats2half2_rn(b.z, b.w);
    uint4 p;
    p.x = *(unsigned int*)&a01;
    p.y = *(unsigned int*)&a23;
    p.z = *(unsigned int*)&b01;
    p.w = *(unsigned int*)&b23;
    volh2[i] = p;
}

__device__ inline float4 h4_to_f4(uint2 p) {
    __half2 ab = *(__half2*)&p.x;
    __half2 cd = *(__half2*)&p.y;
    float2 f0 = __half22float2(ab);
    float2 f1 = __half22float2(cd);
    return make_float4(f0.x, f0.y, f1.x, f1.y);
}

// Per-voxel setup: corner coords + x-base 'a' + 6 weights.
// Edge trick: at the x-clamp edge (ix0 == W-1) the reference result is exactly
// v[W-1]; we use base a = W-2 and force (wx0,wx1) = (0,1) so the high half
// carries the whole weight.
struct VoxSetup {
    int a, iy0, iy1, iz0, iz1;
    float wz0, wz1, wy0, wy1, wx0, wx1;
};

__device__ inline VoxSetup setup_voxel(int x, int y, int z,
                                       float dz, float dy, float dx)
{
    float lz = (float)z + dz;
    float ly = (float)y + dy;
    float lx = (float)x + dx;

    // Reference: loc0c = clip(floor(loc), 0, max); loc1 = clip(loc0c+1, 0, max)
    float z0f = fminf(fmaxf(floorf(lz), 0.f), (float)(D_ - 1));
    float y0f = fminf(fmaxf(floorf(ly), 0.f), (float)(H_ - 1));
    float x0f = fminf(fmaxf(floorf(lx), 0.f), (float)(W_ - 1));
    float z1f = fminf(z0f + 1.f, (float)(D_ - 1));
    float y1f = fminf(y0f + 1.f, (float)(H_ - 1));
    float x1f = fminf(x0f + 1.f, (float)(W_ - 1));

    VoxSetup s;
    s.wz0 = z1f - lz; s.wz1 = 1.f - s.wz0;
    s.wy0 = y1f - ly; s.wy1 = 1.f - s.wy0;

    int ix0 = (int)x0f;
    bool edge = ix0 >= W_ - 1;
    s.a = edge ? W_ - 2 : ix0;
    float wx0 = x1f - lx;
    s.wx0 = edge ? 0.f : wx0;   // edge: result is exactly the high half
    s.wx1 = 1.f - s.wx0;

    s.iz0 = (int)z0f; s.iz1 = (int)z1f;
    s.iy0 = (int)y0f; s.iy1 = (int)y1f;
    return s;
}

// Reduce 4 row-pairs (lo = x0 corner, hi = x1 corner) with weights.
__device__ inline f32x4 reduce_voxel(const VoxSetup& s,
                                     u32x4 q00, u32x4 q01, u32x4 q10, u32x4 q11)
{
    uint2 l00, h00, l01, h01, l10, h10, l11, h11;
    l00.x = q00[0]; l00.y = q00[1]; h00.x = q00[2]; h00.y = q00[3];
    l01.x = q01[0]; l01.y = q01[1]; h01.x = q01[2]; h01.y = q01[3];
    l10.x = q10[0]; l10.y = q10[1]; h10.x = q10[2]; h10.y = q10[3];
    l11.x = q11[0]; l11.y = q11[1]; h11.x = q11[2]; h11.y = q11[3];

    float4 v000 = h4_to_f4(l00), v001 = h4_to_f4(h00);
    float4 v010 = h4_to_f4(l01), v011 = h4_to_f4(h01);
    float4 v100 = h4_to_f4(l10), v101 = h4_to_f4(h10);
    float4 v110 = h4_to_f4(l11), v111 = h4_to_f4(h11);

    float w000 = s.wz0 * s.wy0 * s.wx0;
    float w001 = s.wz0 * s.wy0 * s.wx1;
    float w010 = s.wz0 * s.wy1 * s.wx0;
    float w011 = s.wz0 * s.wy1 * s.wx1;
    float w100 = s.wz1 * s.wy0 * s.wx0;
    float w101 = s.wz1 * s.wy0 * s.wx1;
    float w110 = s.wz1 * s.wy1 * s.wx0;
    float w111 = s.wz1 * s.wy1 * s.wx1;

    f32x4 r;
    r.x = w000 * v000.x + w001 * v001.x + w010 * v010.x + w011 * v011.x
        + w100 * v100.x + w101 * v101.x + w110 * v110.x + w111 * v111.x;
    r.y = w000 * v000.y + w001 * v001.y + w010 * v010.y + w011 * v011.y
        + w100 * v100.y + w101 * v101.y + w110 * v110.y + w111 * v111.y;
    r.z = w000 * v000.z + w001 * v001.z + w010 * v010.z + w011 * v011.z
        + w100 * v100.z + w101 * v101.z + w110 * v110.z + w111 * v111.z;
    r.w = w000 * v000.w + w001 * v001.w + w010 * v010.w + w011 * v011.w
        + w100 * v100.w + w101 * v101.w + w110 * v110.w + w111 * v111.w;
    return r;
}

__device__ inline u32x4 lds_pair(const uint2 (*t)[WY][WX], int zz, int yy, int xx)
{
    uint2 lo = t[zz][yy][xx];
    uint2 hi = t[zz][yy][xx + 1];
    u32x4 q; q[0] = lo.x; q[1] = lo.y; q[2] = hi.x; q[3] = hi.y;
    return q;
}

// ---------------------------------------------------------------------------
// Pass 2: trilinear gather via LDS-staged window.
// Block = 16x4x8 voxels (256 threads, 2 vox/thread at z and z+4). The block's
// gather window (24x14x16 half4 = 43 KB) is bulk-staged global->LDS with
// global_load_lds (42 chunk calls, all in flight, no VGPR destinations --
// sidesteps the R4/R5/R6 failure where the scheduler serialized scattered
// loads to minimize register pressure). Corner reads become ~6-cycle LDS
// reads. ~0.02% of voxels have a corner outside the window (|d| > ~4sigma)
// and take a global-gather fallback branch.
// Grid 10*48*20 = 9600 blocks, XCD-chunked (1200/XCD): XCD k owns
// z in [20k, 20k+20), matching pass 1's slab map (staging hits slab L2).
// ---------------------------------------------------------------------------
__global__ __launch_bounds__(256) void st_half_kernel(
    const uint2* __restrict__ volh,   // [D,H,W] of half4 (8 B)
    const float* __restrict__ df,     // [D,H,W,3]
    float*       __restrict__ out)    // [D,H,W,4] f32
{
    __shared__ alignas(16) uint2 tile[WZ][WY][WX];   // 43,008 B

    // 9600 blocks, bijective XCD chunking: nb = xcd*1200 + bid/8
    unsigned bid = blockIdx.x;
    unsigned nb  = (bid & 7u) * 1200u + (bid >> 3);
    int bx = (int)(nb % 10u);          // 10 x-tiles of 16
    unsigned rest = nb / 10u;
    int by = (int)(rest % 48u);        // 48 y-tiles of 4
    int bz = (int)(rest / 48u);        // 20 z-tiles of 8

    int x_lo = bx * 16 - 4; x_lo = x_lo < 0 ? 0 : (x_lo > W_ - WX ? W_ - WX : x_lo);
    int y_lo = by * 4  - 4; y_lo = y_lo < 0 ? 0 : (y_lo > H_ - WY ? H_ - WY : y_lo);
    int z_lo = bz * 8  - 4; z_lo = z_lo < 0 ? 0 : (z_lo > D_ - WZ ? D_ - WZ : z_lo);

    int tid  = threadIdx.x;
    int lane = tid & 63;
    int wid  = tid >> 6;

    int x  = bx * 16 + (tid & 15);
    int y  = by * 4  + ((tid >> 4) & 3);
    int zA = bz * 8  + wid;            // voxel B at zA + 4

    int idxA = (zA * H_ + y) * W_ + x;
    int idxB = idxA + 4 * H_ * W_;

    // df loads FIRST (oldest in vmcnt order): setup can consume them with a
    // counted vmcnt wait while the 42 staging loads stay in flight.
    const float* dfpA = df + 3 * (size_t)idxA;
    const float* dfpB = df + 3 * (size_t)idxB;
    float dzA = __builtin_nontemporal_load(dfpA + 0);
    float dyA = __builtin_nontemporal_load(dfpA + 1);
    float dxA = __builtin_nontemporal_load(dfpA + 2);
    float dzB = __builtin_nontemporal_load(dfpB + 0);
    float dyB = __builtin_nontemporal_load(dfpB + 1);
    float dxB = __builtin_nontemporal_load(dfpB + 2);

    // Bulk stage the window: 42 x (64 lanes x 16 B) direct global->LDS.
    // Chunk c (wave-uniform) writes LDS bytes [c*1024, c*1024+1024); lane's
    // 16 B = 2 x-adjacent half4 voxels. Window rows are 192 B (multiple of
    // 16) so no chunk straddles a row.
    #pragma unroll
    for (int c0 = 0; c0 < 11; ++c0) {
        int c = c0 * 4 + wid;                 // wave-uniform
        if (c < NSTAGE) {
            int le  = c * 64 + lane;          // 16B-chunk index in window
            int cx  = le % (WX / 2);
            int row = le / (WX / 2);
            int yy  = row % WY;
            int zz  = row / WY;
            const uint2* gp = volh +
                ((size_t)((z_lo + zz) * H_ + (y_lo + yy)) * W_ + x_lo + cx * 2);
            __builtin_amdgcn_global_load_lds(
                (__attribute__((address_space(1))) void*)gp,
                (__attribute__((address_space(3))) void*)
                    ((char*)&tile[0][0][0] + c * 1024),
                16, 0, 0);
        }
    }

    VoxSetup sA = setup_voxel(x, y, zA,     dzA, dyA, dxA);
    VoxSetup sB = setup_voxel(x, y, zA + 4, dzB, dyB, dxB);

    __syncthreads();   // drains staging (vmcnt 0) + barrier

    // ---- voxel A ----
    {
        const VoxSetup& s = sA;
        bool ok = s.a >= x_lo && s.a <= x_lo + WX - 2
               && s.iy0 >= y_lo && s.iy1 <= y_lo + WY - 1
               && s.iz0 >= z_lo && s.iz1 <= z_lo + WZ - 1;
        u32x4 q00, q01, q10, q11;
        if (ok) {
            int xx = s.a - x_lo;
            q00 = lds_pair(tile, s.iz0 - z_lo, s.iy0 - y_lo, xx);
            q01 = lds_pair(tile, s.iz0 - z_lo, s.iy1 - y_lo, xx);
            q10 = lds_pair(tile, s.iz1 - z_lo, s.iy0 - y_lo, xx);
            q11 = lds_pair(tile, s.iz1 - z_lo, s.iy1 - y_lo, xx);
        } else {
            __builtin_memcpy(&q00, volh + ((s.iz0 * H_ + s.iy0) * W_ + s.a), 16);
            __builtin_memcpy(&q01, volh + ((s.iz0 * H_ + s.iy1) * W_ + s.a), 16);
            __builtin_memcpy(&q10, volh + ((s.iz1 * H_ + s.iy0) * W_ + s.a), 16);
            __builtin_memcpy(&q11, volh + ((s.iz1 * H_ + s.iy1) * W_ + s.a), 16);
        }
        f32x4 r = reduce_voxel(s, q00, q01, q10, q11);
        __builtin_nontemporal_store(r, (f32x4*)(out + 4 * (size_t)idxA));
    }
    // ---- voxel B ----
    {
        const VoxSetup& s = sB;
        bool ok = s.a >= x_lo && s.a <= x_lo + WX - 2
               && s.iy0 >= y_lo && s.iy1 <= y_lo + WY - 1
               && s.iz0 >= z_lo && s.iz1 <= z_lo + WZ - 1;
        u32x4 q00, q01, q10, q11;
        if (ok) {
            int xx = s.a - x_lo;
            q00 = lds_pair(tile, s.iz0 - z_lo, s.iy0 - y_lo, xx);
            q01 = lds_pair(tile, s.iz0 - z_lo, s.iy1 - y_lo, xx);
            q10 = lds_pair(tile, s.iz1 - z_lo, s.iy0 - y_lo, xx);
            q11 = lds_pair(tile, s.iz1 - z_lo, s.iy1 - y_lo, xx);
        } else {
            __builtin_memcpy(&q00, volh + ((s.iz0 * H_ + s.iy0) * W_ + s.a), 16);
            __builtin_memcpy(&q01, volh + ((s.iz0 * H_ + s.iy1) * W_ + s.a), 16);
            __builtin_memcpy(&q10, volh + ((s.iz1 * H_ + s.iy0) * W_ + s.a), 16);
            __builtin_memcpy(&q11, volh + ((s.iz1 * H_ + s.iy1) * W_ + s.a), 16);
        }
        f32x4 r = reduce_voxel(s, q00, q01, q10, q11);
        __builtin_nontemporal_store(r, (f32x4*)(out + 4 * (size_t)idxB));
    }
}

// ---------------------------------------------------------------------------
// Fallback (ws too small): pure-f32 gather kernel.
// ---------------------------------------------------------------------------
__global__ __launch_bounds__(256) void st_f32_kernel(
    const float4* __restrict__ vol,
    const float*  __restrict__ df,
    float4*       __restrict__ out)
{
    int tid = threadIdx.x;
    int x = blockIdx.x * 16 + (tid & 15);
    int y = blockIdx.y * 4  + ((tid >> 4) & 3);
    int z = blockIdx.z * 4  + (tid >> 6);
    int idx = (z * H_ + y) * W_ + x;

    float dz = df[3 * idx + 0];
    float dy = df[3 * idx + 1];
    float dx = df[3 * idx + 2];
    float lz = (float)z + dz, ly = (float)y + dy, lx = (float)x + dx;

    float z0f = fminf(fmaxf(floorf(lz), 0.f), (float)(D_ - 1));
    float y0f = fminf(fmaxf(floorf(ly), 0.f), (float)(H_ - 1));
    float x0f = fminf(fmaxf(floorf(lx), 0.f), (float)(W_ - 1));
    float z1f = fminf(z0f + 1.f, (float)(D_ - 1));
    float y1f = fminf(y0f + 1.f, (float)(H_ - 1));
    float x1f = fminf(x0f + 1.f, (float)(W_ - 1));

    float wz0 = z1f - lz, wz1 = 1.f - wz0;
    float wy0 = y1f - ly, wy1 = 1.f - wy0;
    float wx0 = x1f - lx, wx1 = 1.f - wx0;

    int iz0 = (int)z0f, iz1 = (int)z1f;
    int iy0 = (int)y0f, iy1 = (int)y1f;
    int ix0 = (int)x0f, ix1 = (int)x1f;

    int b00 = (iz0 * H_ + iy0) * W_;
    int b01 = (iz0 * H_ + iy1) * W_;
    int b10 = (iz1 * H_ + iy0) * W_;
    int b11 = (iz1 * H_ + iy1) * W_;

    float4 v000 = vol[b00 + ix0];
    float4 v001 = vol[b00 + ix1];
    float4 v010 = vol[b01 + ix0];
    float4 v011 = vol[b01 + ix1];
    float4 v100 = vol[b10 + ix0];
    float4 v101 = vol[b10 + ix1];
    float4 v110 = vol[b11 + ix0];
    float4 v111 = vol[b11 + ix1];

    float w000 = wz0*wy0*wx0, w001 = wz0*wy0*wx1;
    float w010 = wz0*wy1*wx0, w011 = wz0*wy1*wx1;
    float w100 = wz1*wy0*wx0, w101 = wz1*wy0*wx1;
    float w110 = wz1*wy1*wx0, w111 = wz1*wy1*wx1;

    float4 r;
    r.x = w000*v000.x + w001*v001.x + w010*v010.x + w011*v011.x
        + w100*v100.x + w101*v101.x + w110*v110.x + w111*v111.x;
    r.y = w000*v000.y + w001*v001.y + w010*v010.y + w011*v011.y
        + w100*v100.y + w101*v101.y + w110*v110.y + w111*v111.y;
    r.z = w000*v000.z + w001*v001.z + w010*v010.z + w011*v011.z
        + w100*v100.z + w101*v101.z + w110*v110.z + w111*v111.z;
    r.w = w000*v000.w + w001*v001.w + w010*v010.w + w011*v011.w
        + w100*v100.w + w101*v101.w + w110*v110.w + w111*v111.w;

    out[idx] = r;
}

extern "C" void kernel_launch(void* const* d_in, const int* in_sizes, int n_in,
                              void* d_out, int out_size, void* d_ws, size_t ws_size,
                              hipStream_t stream) {
    const float4* vol = (const float4*)d_in[0];  // (160,192,160,4) f32
    const float*  df  = (const float*)d_in[1];   // (160,192,160,3) f32
    float4* out = (float4*)d_out;

    size_t need = (size_t)NV * 8;  // half4 per voxel
    if (ws_size >= need) {
        int pairs = NV / 2;                       // 2,457,600 -> 9600 blocks
        vol_to_half_kernel<<<pairs / 256, 256, 0, stream>>>(
            vol, (uint4*)d_ws);
        st_half_kernel<<<9600, 256, 0, stream>>>(
            (const uint2*)d_ws, df, (float*)out);
    } else {
        dim3 grid(W_ / 16, H_ / 4, D_ / 4);       // 10 x 48 x 40
        st_f32_kernel<<<grid, 256, 0, stream>>>(vol, df, out);
    }
}